// Round 6
// baseline (529.764 us; speedup 1.0000x reference)
//
#include <hip/hip_runtime.h>
#include <hip/hip_cooperative_groups.h>

namespace cg = cooperative_groups;

#define D 128
#define LDW 136      // padded LDS row (bf16 elems): +8 → 2-way bank aliasing (free)
#define MEGA_NB 1024 // coop grid: 1024 blocks x 256 thr = 4096 waves (50% of 8192 capacity)

typedef __attribute__((ext_vector_type(8))) short bf16x8;
typedef __attribute__((ext_vector_type(4))) float f32x4;

static __device__ __forceinline__ ushort f2bf(float f) {
    union { float f; unsigned u; } c; c.f = f;
    unsigned u = c.u;
    return (ushort)((u + 0x7fffu + ((u >> 16) & 1u)) >> 16);  // RNE
}
static __device__ __forceinline__ float bflo(unsigned v) {
    union { unsigned u; float f; } c; c.u = v << 16; return c.f;
}
static __device__ __forceinline__ float bfhi(unsigned v) {
    union { unsigned u; float f; } c; c.u = v & 0xffff0000u; return c.f;
}

// ---------------- coop mega: prep + hist + scan + fill, grid-stride phases ----------------
// grid = MEGA_NB blocks, 256 threads. Scan phase uses only the first ceil(n/256) (<=256) blocks.
__global__ __launch_bounds__(256) void gin_mega(const float* __restrict__ x,
                                                ushort* __restrict__ xb, int n4,
                                                const float* __restrict__ W,
                                                ushort* __restrict__ Wb, int w4,
                                                const int* __restrict__ src,
                                                const int* __restrict__ dst,
                                                int* __restrict__ deg, int ndeg4,
                                                int* __restrict__ bsum,
                                                int* __restrict__ rowptr,
                                                int* __restrict__ cursor,
                                                int* __restrict__ csr_src,
                                                int nnodes, int nedges) {
    cg::grid_group grid = cg::this_grid();
    __shared__ int sh[256];

    int tid = threadIdx.x;
    int bid = blockIdx.x;
    int nthreads = gridDim.x * 256;
    int gtid = bid * 256 + tid;
    int nb_scan = (nnodes + 255) >> 8;

    // phase 0: zero deg, cvt x->bf16, cvt W->bf16
    for (int i = gtid; i < ndeg4; i += nthreads)
        ((int4*)deg)[i] = make_int4(0, 0, 0, 0);
    for (int i = gtid; i < n4; i += nthreads) {
        float4 v = ((const float4*)x)[i];
        ushort4 o;
        o.x = f2bf(v.x); o.y = f2bf(v.y); o.z = f2bf(v.z); o.w = f2bf(v.w);
        ((ushort4*)xb)[i] = o;
    }
    for (int i = gtid; i < w4; i += nthreads) {
        float4 v = ((const float4*)W)[i];
        ushort4 o;
        o.x = f2bf(v.x); o.y = f2bf(v.y); o.z = f2bf(v.z); o.w = f2bf(v.w);
        ((ushort4*)Wb)[i] = o;
    }
    grid.sync();

    // phase A: histogram (grid-stride, ~2.3 edges/thread)
    for (int e = gtid; e < nedges; e += nthreads)
        atomicAdd(&deg[dst[e]], 1);
    grid.sync();

    // phase B+C: scan — only first nb_scan blocks have work (block-uniform branch)
    if (bid < nb_scan) {
        int i = bid * 256 + tid;                  // node index
        int dv = (i < nnodes) ? deg[i] : 0;

        // B: per-block sum
        sh[tid] = dv;
        __syncthreads();
        for (int off = 128; off > 0; off >>= 1) {
            if (tid < off) sh[tid] += sh[tid + off];
            __syncthreads();
        }
        if (tid == 0) bsum[bid] = sh[0];
        __syncthreads();
        grid.sync();

        // C1: block offset = sum bsum[0..bid)  (tid < bid <= nb_scan-1 => in range)
        int bv = (tid < bid) ? bsum[tid] : 0;
        sh[tid] = bv;
        __syncthreads();
        for (int off = 128; off > 0; off >>= 1) {
            if (tid < off) sh[tid] += sh[tid + off];
            __syncthreads();
        }
        int boffset = sh[0];
        __syncthreads();

        // C2: block-local inclusive scan -> exclusive + offset
        sh[tid] = dv;
        __syncthreads();
        for (int off = 1; off < 256; off <<= 1) {
            int t = (tid >= off) ? sh[tid - off] : 0;
            __syncthreads();
            sh[tid] += t;
            __syncthreads();
        }
        int ex = boffset + sh[tid] - dv;
        if (i < nnodes) {
            rowptr[i] = ex;
            cursor[i] = ex;
        }
        if (i == 0) rowptr[nnodes] = nedges;
    } else {
        grid.sync();   // match phase-B->C grid.sync
    }
    grid.sync();

    // phase D: fill buckets (grid-stride)
    for (int e = gtid; e < nedges; e += nthreads) {
        int pos = atomicAdd(&cursor[dst[e]], 1);
        csr_src[pos] = src[e];
    }
}

// ---------------- fallback non-coop kernels (R4-proven path) ----------------
__global__ __launch_bounds__(256) void gin_prep(const float* __restrict__ x,
                                                ushort* __restrict__ xb, int n4,
                                                const float* __restrict__ W,
                                                ushort* __restrict__ Wb, int w4,
                                                int* __restrict__ deg, int ndeg4) {
    int stride = gridDim.x * 256;
    int tid0 = blockIdx.x * 256 + threadIdx.x;
    for (int i = tid0; i < ndeg4; i += stride)
        ((int4*)deg)[i] = make_int4(0, 0, 0, 0);
    for (int i = tid0; i < n4; i += stride) {
        float4 v = ((const float4*)x)[i];
        ushort4 o;
        o.x = f2bf(v.x); o.y = f2bf(v.y); o.z = f2bf(v.z); o.w = f2bf(v.w);
        ((ushort4*)xb)[i] = o;
    }
    for (int i = tid0; i < w4; i += stride) {
        float4 v = ((const float4*)W)[i];
        ushort4 o;
        o.x = f2bf(v.x); o.y = f2bf(v.y); o.z = f2bf(v.z); o.w = f2bf(v.w);
        ((ushort4*)Wb)[i] = o;
    }
}
__global__ __launch_bounds__(256) void gin_hist(const int* __restrict__ dst,
                                                int* __restrict__ deg, int nedges) {
    int e = blockIdx.x * 256 + threadIdx.x;
    if (e < nedges) atomicAdd(&deg[dst[e]], 1);
}
__global__ __launch_bounds__(256) void gin_bsum(const int* __restrict__ deg,
                                                int* __restrict__ bsum, int n) {
    __shared__ int sh[256];
    int i = blockIdx.x * 256 + threadIdx.x;
    int v = (i < n) ? deg[i] : 0;
    sh[threadIdx.x] = v;
    __syncthreads();
    for (int off = 128; off > 0; off >>= 1) {
        if (threadIdx.x < off) sh[threadIdx.x] += sh[threadIdx.x + off];
        __syncthreads();
    }
    if (threadIdx.x == 0) bsum[blockIdx.x] = sh[0];
}
__global__ __launch_bounds__(256) void gin_bscan(const int* __restrict__ bsum,
                                                 int* __restrict__ boff,
                                                 int* __restrict__ rowptr,
                                                 int nb, int n) {
    __shared__ int sh[256];
    int i = threadIdx.x;
    int v = (i < nb) ? bsum[i] : 0;
    sh[i] = v;
    __syncthreads();
    for (int off = 1; off < 256; off <<= 1) {
        int t = (i >= off) ? sh[i - off] : 0;
        __syncthreads();
        sh[i] += t;
        __syncthreads();
    }
    if (i < nb) boff[i] = sh[i] - v;
    if (i == 255) rowptr[n] = sh[255];
}
__global__ __launch_bounds__(256) void gin_scan(const int* __restrict__ deg,
                                                const int* __restrict__ boff,
                                                int* __restrict__ rowptr,
                                                int* __restrict__ cursor, int n) {
    __shared__ int sh[256];
    int i = blockIdx.x * 256 + threadIdx.x;
    int v = (i < n) ? deg[i] : 0;
    sh[threadIdx.x] = v;
    __syncthreads();
    for (int off = 1; off < 256; off <<= 1) {
        int t = (threadIdx.x >= off) ? sh[threadIdx.x - off] : 0;
        __syncthreads();
        sh[threadIdx.x] += t;
        __syncthreads();
    }
    if (i < n) {
        int ex = boff[blockIdx.x] + sh[threadIdx.x] - v;
        rowptr[i] = ex;
        cursor[i] = ex;
    }
}
__global__ __launch_bounds__(256) void gin_fill(const int* __restrict__ src,
                                                const int* __restrict__ dst,
                                                int* __restrict__ cursor,
                                                int* __restrict__ csr_src, int nedges) {
    int e = blockIdx.x * 256 + threadIdx.x;
    if (e < nedges) {
        int pos = atomicAdd(&cursor[dst[e]], 1);
        csr_src[pos] = src[e];
    }
}

// ---------------- gather (bf16): hb[i] = bf16( x[i] + sum_e xb[csr_src[e]] ) ----------------
__global__ __launch_bounds__(256) void gin_gather_bf(const float* __restrict__ x,
                                                     const ushort* __restrict__ xb,
                                                     const int* __restrict__ rowptr,
                                                     const int* __restrict__ csr_src,
                                                     ushort* __restrict__ hb, int nnodes) {
    int wave = blockIdx.x * 4 + (threadIdx.x >> 6);
    int lane = threadIdx.x & 63;
    if (wave >= nnodes) return;

    int beg = rowptr[wave];
    int end = rowptr[wave + 1];

    float2 acc = *(const float2*)&x[(size_t)wave * D + lane * 2];  // self term fp32 (eps=0)
    const unsigned* xbu = (const unsigned*)xb;

    int e = beg;
    for (; e + 8 <= end; e += 8) {
        int s0 = csr_src[e],     s1 = csr_src[e + 1];
        int s2 = csr_src[e + 2], s3 = csr_src[e + 3];
        int s4 = csr_src[e + 4], s5 = csr_src[e + 5];
        int s6 = csr_src[e + 6], s7 = csr_src[e + 7];
        unsigned v0 = xbu[(size_t)s0 * 64 + lane];
        unsigned v1 = xbu[(size_t)s1 * 64 + lane];
        unsigned v2 = xbu[(size_t)s2 * 64 + lane];
        unsigned v3 = xbu[(size_t)s3 * 64 + lane];
        unsigned v4 = xbu[(size_t)s4 * 64 + lane];
        unsigned v5 = xbu[(size_t)s5 * 64 + lane];
        unsigned v6 = xbu[(size_t)s6 * 64 + lane];
        unsigned v7 = xbu[(size_t)s7 * 64 + lane];
        acc.x += ((bflo(v0) + bflo(v1)) + (bflo(v2) + bflo(v3)))
               + ((bflo(v4) + bflo(v5)) + (bflo(v6) + bflo(v7)));
        acc.y += ((bfhi(v0) + bfhi(v1)) + (bfhi(v2) + bfhi(v3)))
               + ((bfhi(v4) + bfhi(v5)) + (bfhi(v6) + bfhi(v7)));
    }
    if (e + 4 <= end) {
        int s0 = csr_src[e],     s1 = csr_src[e + 1];
        int s2 = csr_src[e + 2], s3 = csr_src[e + 3];
        unsigned v0 = xbu[(size_t)s0 * 64 + lane];
        unsigned v1 = xbu[(size_t)s1 * 64 + lane];
        unsigned v2 = xbu[(size_t)s2 * 64 + lane];
        unsigned v3 = xbu[(size_t)s3 * 64 + lane];
        acc.x += (bflo(v0) + bflo(v1)) + (bflo(v2) + bflo(v3));
        acc.y += (bfhi(v0) + bfhi(v1)) + (bfhi(v2) + bfhi(v3));
        e += 4;
    }
    for (; e < end; ++e) {
        unsigned v = xbu[(size_t)csr_src[e] * 64 + lane];
        acc.x += bflo(v);
        acc.y += bfhi(v);
    }
    unsigned o = (unsigned)f2bf(acc.x) | ((unsigned)f2bf(acc.y) << 16);
    ((unsigned*)hb)[(size_t)wave * 64 + lane] = o;
}

// ---------------- MFMA GEMM: out = hb @ Wb^T + b (bf16 in, fp32 out) ----------------
__global__ __launch_bounds__(256) void gin_gemm_mfma(const ushort* __restrict__ hb,
                                                     const ushort* __restrict__ Wb,
                                                     const float* __restrict__ bias,
                                                     float* __restrict__ out, int nrows) {
    __shared__ ushort Wl[D * LDW];
    __shared__ ushort Al[64 * LDW];

    int tid = threadIdx.x;

    for (int i = tid; i < D * D / 8; i += 256) {
        uint4 v = ((const uint4*)Wb)[i];
        int row = i >> 4;
        int col = (i & 15) * 8;
        *(uint4*)&Wl[row * LDW + col] = v;
    }

    int base = blockIdx.x * 64;
    for (int j = tid; j < 1024; j += 256) {
        int row = j >> 4;
        int col = (j & 15) * 8;
        uint4 v = make_uint4(0, 0, 0, 0);
        if (base + row < nrows) v = *(const uint4*)&hb[(size_t)(base + row) * D + col];
        *(uint4*)&Al[row * LDW + col] = v;
    }
    __syncthreads();

    int w = tid >> 6, l = tid & 63;
    int wr = w >> 1, wc = w & 1;
    int lr = l & 15, hi = l >> 4;

    f32x4 acc[2][4];
#pragma unroll
    for (int m = 0; m < 2; m++)
#pragma unroll
        for (int t = 0; t < 4; t++) acc[m][t] = (f32x4)0.0f;

#pragma unroll
    for (int ks = 0; ks < 4; ks++) {
        int kof = ks * 32 + hi * 8;
        bf16x8 a0 = *(bf16x8*)&Al[(wr * 32 + lr) * LDW + kof];
        bf16x8 a1 = *(bf16x8*)&Al[(wr * 32 + 16 + lr) * LDW + kof];
#pragma unroll
        for (int t = 0; t < 4; t++) {
            bf16x8 bm = *(bf16x8*)&Wl[(wc * 64 + t * 16 + lr) * LDW + kof];
            acc[0][t] = __builtin_amdgcn_mfma_f32_16x16x32_bf16(a0, bm, acc[0][t], 0, 0, 0);
            acc[1][t] = __builtin_amdgcn_mfma_f32_16x16x32_bf16(a1, bm, acc[1][t], 0, 0, 0);
        }
    }

    // C/D layout (m89-verified): col = lane&15, row = (lane>>4)*4 + reg
#pragma unroll
    for (int m = 0; m < 2; m++) {
#pragma unroll
        for (int t = 0; t < 4; t++) {
            int col = wc * 64 + t * 16 + lr;
            float bv = bias[col];
#pragma unroll
            for (int r = 0; r < 4; r++) {
                int row = base + wr * 32 + m * 16 + hi * 4 + r;
                if (row < nrows) out[(size_t)row * D + col] = acc[m][t][r] + bv;
            }
        }
    }
}

extern "C" void kernel_launch(void* const* d_in, const int* in_sizes, int n_in,
                              void* d_out, int out_size, void* d_ws, size_t ws_size,
                              hipStream_t stream) {
    const float* x  = (const float*)d_in[0];
    const int*   ei = (const int*)d_in[1];
    const float* W  = (const float*)d_in[2];
    const float* bb = (const float*)d_in[3];
    float* out = (float*)d_out;

    int nnodes = in_sizes[0] / D;
    int nedges = in_sizes[1] / 2;
    const int* srcp = ei;
    const int* dstp = ei + nedges;

    int nb = (nnodes + 255) / 256;
    int npad = nb * 256;

    // workspace layout
    char* p = (char*)d_ws;
    int* deg     = (int*)p;  p += (size_t)npad * 4;
    int* rowptr  = (int*)p;  p += (size_t)(nnodes + 1) * 4;
    int* cursor  = (int*)p;  p += (size_t)npad * 4;
    int* bsum    = (int*)p;  p += 256 * 4;
    int* boff    = (int*)p;  p += 256 * 4;
    int* csr_src = (int*)p;  p += (size_t)nedges * 4;
    p = (char*)(((uintptr_t)p + 15) & ~(uintptr_t)15);
    ushort* xb = (ushort*)p; p += (size_t)nnodes * D * 2;
    ushort* hb = (ushort*)p; p += (size_t)nnodes * D * 2;
    ushort* Wb = (ushort*)p; p += (size_t)D * D * 2;

    int n4 = nnodes * (D / 4);
    int w4 = D * D / 4;
    int ndeg4 = npad / 4;

    // 1) coop mega: prep + hist + scan + fill (grid-stride at 1024 blocks)
    bool coop_ok = (nb <= 256);
    if (coop_ok) {
        void* args[] = {(void*)&x, (void*)&xb, (void*)&n4, (void*)&W, (void*)&Wb,
                        (void*)&w4, (void*)&srcp, (void*)&dstp, (void*)&deg,
                        (void*)&ndeg4, (void*)&bsum, (void*)&rowptr, (void*)&cursor,
                        (void*)&csr_src, (void*)&nnodes, (void*)&nedges};
        hipError_t err = hipLaunchCooperativeKernel((void*)gin_mega, dim3(MEGA_NB),
                                                    dim3(256), args, 0, stream);
        if (err != hipSuccess) coop_ok = false;
    }
    if (!coop_ok) {
        gin_prep<<<2048, 256, 0, stream>>>(x, xb, n4, W, Wb, w4, deg, ndeg4);
        int eb = (nedges + 255) / 256;
        gin_hist<<<eb, 256, 0, stream>>>(dstp, deg, nedges);
        gin_bsum<<<nb, 256, 0, stream>>>(deg, bsum, nnodes);
        gin_bscan<<<1, 256, 0, stream>>>(bsum, boff, rowptr, nb, nnodes);
        gin_scan<<<nb, 256, 0, stream>>>(deg, boff, rowptr, cursor, nnodes);
        gin_fill<<<eb, 256, 0, stream>>>(srcp, dstp, cursor, csr_src, nedges);
    }

    // 2) gather: one wave per node
    int gb = (nnodes + 3) / 4;
    gin_gather_bf<<<gb, 256, 0, stream>>>(x, xb, rowptr, csr_src, hb, nnodes);

    // 3) GEMM
    int gemb = (nnodes + 63) / 64;
    gin_gemm_mfma<<<gemb, 256, 0, stream>>>(hb, Wb, bb, out, nnodes);
}

// Round 7
// 185.599 us; speedup vs baseline: 2.8543x; 2.8543x over previous
//
#include <hip/hip_runtime.h>

#define D 128
#define LDW 136   // padded LDS row (bf16 elems): +8 → 2-way bank aliasing (free)

typedef __attribute__((ext_vector_type(8))) short bf16x8;
typedef __attribute__((ext_vector_type(4))) float f32x4;

static __device__ __forceinline__ ushort f2bf(float f) {
    union { float f; unsigned u; } c; c.f = f;
    unsigned u = c.u;
    return (ushort)((u + 0x7fffu + ((u >> 16) & 1u)) >> 16);  // RNE
}
static __device__ __forceinline__ float bflo(unsigned v) {
    union { unsigned u; float f; } c; c.u = v << 16; return c.f;
}
static __device__ __forceinline__ float bfhi(unsigned v) {
    union { unsigned u; float f; } c; c.u = v & 0xffff0000u; return c.f;
}

// ---------------- prep: deg = 0, xb = bf16(x), Wb = bf16(W) ----------------
__global__ __launch_bounds__(256) void gin_prep(const float* __restrict__ x,
                                                ushort* __restrict__ xb, int n4,
                                                const float* __restrict__ W,
                                                ushort* __restrict__ Wb, int w4,
                                                int* __restrict__ deg, int ndeg4) {
    int stride = gridDim.x * 256;
    int tid0 = blockIdx.x * 256 + threadIdx.x;
    for (int i = tid0; i < ndeg4; i += stride)
        ((int4*)deg)[i] = make_int4(0, 0, 0, 0);
    for (int i = tid0; i < n4; i += stride) {
        float4 v = ((const float4*)x)[i];
        ushort4 o;
        o.x = f2bf(v.x); o.y = f2bf(v.y); o.z = f2bf(v.z); o.w = f2bf(v.w);
        ((ushort4*)xb)[i] = o;
    }
    for (int i = tid0; i < w4; i += stride) {
        float4 v = ((const float4*)W)[i];
        ushort4 o;
        o.x = f2bf(v.x); o.y = f2bf(v.y); o.z = f2bf(v.z); o.w = f2bf(v.w);
        ((ushort4*)Wb)[i] = o;
    }
}

// ---------------- hist: deg[dst]++ ----------------
__global__ __launch_bounds__(256) void gin_hist(const int* __restrict__ dst,
                                                int* __restrict__ deg, int nedges) {
    int e = blockIdx.x * 256 + threadIdx.x;
    if (e < nedges) atomicAdd(&deg[dst[e]], 1);
}

// ---------------- scanall: rowptr/cursor = exclusive_scan(deg), one kernel ----------------
// block b redundantly reduces deg[0 .. b*256) itself (no cross-block comms, no sync),
// then block-scans its own 256-node chunk. Total redundant reads ~nb^2/2*256 ints = ~20 MB of L2.
__global__ __launch_bounds__(256) void gin_scanall(const int* __restrict__ deg,
                                                   int* __restrict__ rowptr,
                                                   int* __restrict__ cursor,
                                                   int nnodes, int nedges) {
    __shared__ int sh[256];
    int tid = threadIdx.x;
    int bid = blockIdx.x;
    int lim = bid * 256;

    // prefix over all earlier chunks
    int s = 0;
    for (int i = tid; i < lim; i += 256) s += deg[i];
    sh[tid] = s;
    __syncthreads();
    for (int off = 128; off > 0; off >>= 1) {
        if (tid < off) sh[tid] += sh[tid + off];
        __syncthreads();
    }
    int prefix = sh[0];
    __syncthreads();

    // local inclusive scan of this chunk
    int i = lim + tid;
    int dv = (i < nnodes) ? deg[i] : 0;
    sh[tid] = dv;
    __syncthreads();
    for (int off = 1; off < 256; off <<= 1) {
        int t = (tid >= off) ? sh[tid - off] : 0;
        __syncthreads();
        sh[tid] += t;
        __syncthreads();
    }
    int ex = prefix + sh[tid] - dv;
    if (i < nnodes) {
        rowptr[i] = ex;
        cursor[i] = ex;
    }
    if (bid == (int)gridDim.x - 1 && tid == 0) rowptr[nnodes] = nedges;
}

// ---------------- fill: scatter edges into CSR buckets ----------------
__global__ __launch_bounds__(256) void gin_fill(const int* __restrict__ src,
                                                const int* __restrict__ dst,
                                                int* __restrict__ cursor,
                                                int* __restrict__ csr_src, int nedges) {
    int e = blockIdx.x * 256 + threadIdx.x;
    if (e < nedges) {
        int pos = atomicAdd(&cursor[dst[e]], 1);
        csr_src[pos] = src[e];
    }
}

// ---------------- fused gather + MFMA GEMM ----------------
// block = 256 thr = 4 waves, 64-node tile.
// Phase 1 (gather): wave w gathers nodes [base+w*16, base+w*16+16) into Al:
//   Al[row][:] = bf16( xb[node] + sum_e xb[csr_src[e]] ), lane owns 4B (2 bf16) of the 256B row.
// Phase 2 (GEMM): 2x2 wave grid, 16x16x32 bf16 MFMA, out = Al @ Wl^T + b.
// 52 KB LDS -> 3 blocks/CU; one block's gather overlaps another's MFMA.
__global__ __launch_bounds__(256) void gin_fused(const ushort* __restrict__ xb,
                                                 const int* __restrict__ rowptr,
                                                 const int* __restrict__ csr_src,
                                                 const ushort* __restrict__ Wb,
                                                 const float* __restrict__ bias,
                                                 float* __restrict__ out, int nnodes) {
    __shared__ ushort Wl[D * LDW];
    __shared__ ushort Al[64 * LDW];

    int tid = threadIdx.x;
    int base = blockIdx.x * 64;

    // stage Wb (bf16, 32 KB) as 2048 uint4 chunks
    for (int i = tid; i < D * D / 8; i += 256) {
        uint4 v = ((const uint4*)Wb)[i];
        int row = i >> 4;
        int col = (i & 15) * 8;
        *(uint4*)&Wl[row * LDW + col] = v;
    }

    // gather phase: wave w -> 16 sequential nodes
    {
        int w = tid >> 6, lane = tid & 63;
        const unsigned* xbu = (const unsigned*)xb;  // 1 uint = 2 bf16
        for (int t = 0; t < 16; ++t) {
            int row = w * 16 + t;
            int node = base + row;
            unsigned ov = 0;
            if (node < nnodes) {
                int beg = rowptr[node];
                int end = rowptr[node + 1];
                unsigned sv = xbu[(size_t)node * 64 + lane];       // self term (eps=0), bf16
                float2 acc;
                acc.x = bflo(sv);
                acc.y = bfhi(sv);
                int e = beg;
                for (; e + 8 <= end; e += 8) {
                    int s0 = csr_src[e],     s1 = csr_src[e + 1];
                    int s2 = csr_src[e + 2], s3 = csr_src[e + 3];
                    int s4 = csr_src[e + 4], s5 = csr_src[e + 5];
                    int s6 = csr_src[e + 6], s7 = csr_src[e + 7];
                    unsigned v0 = xbu[(size_t)s0 * 64 + lane];
                    unsigned v1 = xbu[(size_t)s1 * 64 + lane];
                    unsigned v2 = xbu[(size_t)s2 * 64 + lane];
                    unsigned v3 = xbu[(size_t)s3 * 64 + lane];
                    unsigned v4 = xbu[(size_t)s4 * 64 + lane];
                    unsigned v5 = xbu[(size_t)s5 * 64 + lane];
                    unsigned v6 = xbu[(size_t)s6 * 64 + lane];
                    unsigned v7 = xbu[(size_t)s7 * 64 + lane];
                    acc.x += ((bflo(v0) + bflo(v1)) + (bflo(v2) + bflo(v3)))
                           + ((bflo(v4) + bflo(v5)) + (bflo(v6) + bflo(v7)));
                    acc.y += ((bfhi(v0) + bfhi(v1)) + (bfhi(v2) + bfhi(v3)))
                           + ((bfhi(v4) + bfhi(v5)) + (bfhi(v6) + bfhi(v7)));
                }
                if (e + 4 <= end) {
                    int s0 = csr_src[e],     s1 = csr_src[e + 1];
                    int s2 = csr_src[e + 2], s3 = csr_src[e + 3];
                    unsigned v0 = xbu[(size_t)s0 * 64 + lane];
                    unsigned v1 = xbu[(size_t)s1 * 64 + lane];
                    unsigned v2 = xbu[(size_t)s2 * 64 + lane];
                    unsigned v3 = xbu[(size_t)s3 * 64 + lane];
                    acc.x += (bflo(v0) + bflo(v1)) + (bflo(v2) + bflo(v3));
                    acc.y += (bfhi(v0) + bfhi(v1)) + (bfhi(v2) + bfhi(v3));
                    e += 4;
                }
                for (; e < end; ++e) {
                    unsigned v = xbu[(size_t)csr_src[e] * 64 + lane];
                    acc.x += bflo(v);
                    acc.y += bfhi(v);
                }
                ov = (unsigned)f2bf(acc.x) | ((unsigned)f2bf(acc.y) << 16);
            }
            *(unsigned*)&Al[row * LDW + lane * 2] = ov;   // 64 lanes x 4B consecutive: conflict-free
        }
    }
    __syncthreads();

    // MFMA phase
    int w = tid >> 6, l = tid & 63;
    int wr = w >> 1, wc = w & 1;     // 2x2 wave grid: 32 rows x 64 cols per wave
    int lr = l & 15, hi = l >> 4;

    f32x4 acc[2][4];
#pragma unroll
    for (int m = 0; m < 2; m++)
#pragma unroll
        for (int t = 0; t < 4; t++) acc[m][t] = (f32x4)0.0f;

#pragma unroll
    for (int ks = 0; ks < 4; ks++) {
        int kof = ks * 32 + hi * 8;
        bf16x8 a0 = *(bf16x8*)&Al[(wr * 32 + lr) * LDW + kof];
        bf16x8 a1 = *(bf16x8*)&Al[(wr * 32 + 16 + lr) * LDW + kof];
#pragma unroll
        for (int t = 0; t < 4; t++) {
            bf16x8 bm = *(bf16x8*)&Wl[(wc * 64 + t * 16 + lr) * LDW + kof];
            acc[0][t] = __builtin_amdgcn_mfma_f32_16x16x32_bf16(a0, bm, acc[0][t], 0, 0, 0);
            acc[1][t] = __builtin_amdgcn_mfma_f32_16x16x32_bf16(a1, bm, acc[1][t], 0, 0, 0);
        }
    }

    // C/D layout (m89-verified): col = lane&15, row = (lane>>4)*4 + reg
#pragma unroll
    for (int m = 0; m < 2; m++) {
#pragma unroll
        for (int t = 0; t < 4; t++) {
            int col = wc * 64 + t * 16 + lr;
            float bv = bias[col];
#pragma unroll
            for (int r = 0; r < 4; r++) {
                int row = base + wr * 32 + m * 16 + hi * 4 + r;
                if (row < nnodes) out[(size_t)row * D + col] = acc[m][t][r] + bv;
            }
        }
    }
}

extern "C" void kernel_launch(void* const* d_in, const int* in_sizes, int n_in,
                              void* d_out, int out_size, void* d_ws, size_t ws_size,
                              hipStream_t stream) {
    const float* x  = (const float*)d_in[0];
    const int*   ei = (const int*)d_in[1];
    const float* W  = (const float*)d_in[2];
    const float* bb = (const float*)d_in[3];
    float* out = (float*)d_out;

    int nnodes = in_sizes[0] / D;
    int nedges = in_sizes[1] / 2;
    const int* srcp = ei;
    const int* dstp = ei + nedges;

    int nb = (nnodes + 255) / 256;
    int npad = nb * 256;

    // workspace layout
    char* p = (char*)d_ws;
    int* deg     = (int*)p;  p += (size_t)npad * 4;
    int* rowptr  = (int*)p;  p += (size_t)(nnodes + 1) * 4;
    int* cursor  = (int*)p;  p += (size_t)npad * 4;
    int* csr_src = (int*)p;  p += (size_t)nedges * 4;
    p = (char*)(((uintptr_t)p + 15) & ~(uintptr_t)15);
    ushort* xb = (ushort*)p; p += (size_t)nnodes * D * 2;
    ushort* Wb = (ushort*)p; p += (size_t)D * D * 2;

    int n4 = nnodes * (D / 4);
    int w4 = D * D / 4;
    int ndeg4 = npad / 4;
    int eb = (nedges + 255) / 256;

    // 1) prep: zero deg + cvt x->bf16 + cvt W->bf16
    gin_prep<<<2048, 256, 0, stream>>>(x, xb, n4, W, Wb, w4, deg, ndeg4);

    // 2) hist
    gin_hist<<<eb, 256, 0, stream>>>(dstp, deg, nedges);

    // 3) scan (single kernel, redundant block-prefix — no cross-block sync)
    gin_scanall<<<nb, 256, 0, stream>>>(deg, rowptr, cursor, nnodes, nedges);

    // 4) fill
    gin_fill<<<eb, 256, 0, stream>>>(srcp, dstp, cursor, csr_src, nedges);

    // 5) fused gather + GEMM
    int gemb = (nnodes + 63) / 64;
    gin_fused<<<gemb, 256, 0, stream>>>(xb, rowptr, csr_src, Wb, bb, out, nnodes);
}

// Round 8
// 147.618 us; speedup vs baseline: 3.5887x; 1.2573x over previous
//
#include <hip/hip_runtime.h>

#define D 128
#define LDW 136   // padded LDS row (bf16 elems): +8 → 2-way bank aliasing (free)

typedef __attribute__((ext_vector_type(8))) short bf16x8;
typedef __attribute__((ext_vector_type(4))) float f32x4;

static __device__ __forceinline__ ushort f2bf(float f) {
    union { float f; unsigned u; } c; c.f = f;
    unsigned u = c.u;
    return (ushort)((u + 0x7fffu + ((u >> 16) & 1u)) >> 16);  // RNE
}
static __device__ __forceinline__ float bflo(unsigned v) {
    union { unsigned u; float f; } c; c.u = v << 16; return c.f;
}
static __device__ __forceinline__ float bfhi(unsigned v) {
    union { unsigned u; float f; } c; c.u = v & 0xffff0000u; return c.f;
}

// ---------------- prep: deg = 0, xb = bf16(x), Wb = bf16(W) ----------------
__global__ __launch_bounds__(256) void gin_prep(const float* __restrict__ x,
                                                ushort* __restrict__ xb, int n4,
                                                const float* __restrict__ W,
                                                ushort* __restrict__ Wb, int w4,
                                                int* __restrict__ deg, int ndeg4) {
    int stride = gridDim.x * 256;
    int tid0 = blockIdx.x * 256 + threadIdx.x;
    for (int i = tid0; i < ndeg4; i += stride)
        ((int4*)deg)[i] = make_int4(0, 0, 0, 0);
    for (int i = tid0; i < n4; i += stride) {
        float4 v = ((const float4*)x)[i];
        ushort4 o;
        o.x = f2bf(v.x); o.y = f2bf(v.y); o.z = f2bf(v.z); o.w = f2bf(v.w);
        ((ushort4*)xb)[i] = o;
    }
    for (int i = tid0; i < w4; i += stride) {
        float4 v = ((const float4*)W)[i];
        ushort4 o;
        o.x = f2bf(v.x); o.y = f2bf(v.y); o.z = f2bf(v.z); o.w = f2bf(v.w);
        ((ushort4*)Wb)[i] = o;
    }
}

// ---------------- hist: deg[dst]++ ----------------
__global__ __launch_bounds__(256) void gin_hist(const int* __restrict__ dst,
                                                int* __restrict__ deg, int nedges) {
    int e = blockIdx.x * 256 + threadIdx.x;
    if (e < nedges) atomicAdd(&deg[dst[e]], 1);
}

// ---------------- scanall: rowptr/cursor = exclusive_scan(deg) ----------------
// block b redundantly reduces deg[0 .. b*256) (no cross-block comms), then scans its chunk
__global__ __launch_bounds__(256) void gin_scanall(const int* __restrict__ deg,
                                                   int* __restrict__ rowptr,
                                                   int* __restrict__ cursor,
                                                   int nnodes, int nedges) {
    __shared__ int sh[256];
    int tid = threadIdx.x;
    int bid = blockIdx.x;
    int lim = bid * 256;

    int s = 0;
    for (int i = tid; i < lim; i += 256) s += deg[i];
    sh[tid] = s;
    __syncthreads();
    for (int off = 128; off > 0; off >>= 1) {
        if (tid < off) sh[tid] += sh[tid + off];
        __syncthreads();
    }
    int prefix = sh[0];
    __syncthreads();

    int i = lim + tid;
    int dv = (i < nnodes) ? deg[i] : 0;
    sh[tid] = dv;
    __syncthreads();
    for (int off = 1; off < 256; off <<= 1) {
        int t = (tid >= off) ? sh[tid - off] : 0;
        __syncthreads();
        sh[tid] += t;
        __syncthreads();
    }
    int ex = prefix + sh[tid] - dv;
    if (i < nnodes) {
        rowptr[i] = ex;
        cursor[i] = ex;
    }
    if (bid == (int)gridDim.x - 1 && tid == 0) rowptr[nnodes] = nedges;
}

// ---------------- fill: scatter edges into CSR buckets ----------------
__global__ __launch_bounds__(256) void gin_fill(const int* __restrict__ src,
                                                const int* __restrict__ dst,
                                                int* __restrict__ cursor,
                                                int* __restrict__ csr_src, int nedges) {
    int e = blockIdx.x * 256 + threadIdx.x;
    if (e < nedges) {
        int pos = atomicAdd(&cursor[dst[e]], 1);
        csr_src[pos] = src[e];
    }
}

// ---------------- gather (bf16): hb[i] = bf16( xb[i] + sum_e xb[csr_src[e]] ) ----------------
// one wave per node; lane owns 4B (2 bf16) of the 256B row.
// masked 16-deep batches: ceil(deg/16) batches, tail indices clamped to end-1 (L1-broadcast),
// adds predicated — every edge-row load is 16-deep pipelined (no serial tail).
__global__ __launch_bounds__(256) void gin_gather_bf(const ushort* __restrict__ xb,
                                                     const int* __restrict__ rowptr,
                                                     const int* __restrict__ csr_src,
                                                     ushort* __restrict__ hb, int nnodes) {
    int wave = blockIdx.x * 4 + (threadIdx.x >> 6);
    int lane = threadIdx.x & 63;
    if (wave >= nnodes) return;

    int beg = rowptr[wave];
    int end = rowptr[wave + 1];

    const unsigned* xbu = (const unsigned*)xb;  // 1 uint = 2 bf16
    unsigned sv = xbu[(size_t)wave * 64 + lane];
    float2 acc;
    acc.x = bflo(sv);                            // self term (eps=0)
    acc.y = bfhi(sv);

    if (end > beg) {
        int last = end - 1;
        for (int e0 = beg; e0 < end; e0 += 16) {
            int idx[16];
            unsigned v[16];
#pragma unroll
            for (int k = 0; k < 16; ++k) {
                int ee = e0 + k;
                idx[k] = csr_src[ee <= last ? ee : last];
            }
#pragma unroll
            for (int k = 0; k < 16; ++k)
                v[k] = xbu[(size_t)idx[k] * 64 + lane];
#pragma unroll
            for (int k = 0; k < 16; ++k) {
                bool m = (e0 + k) <= last;
                acc.x += m ? bflo(v[k]) : 0.0f;
                acc.y += m ? bfhi(v[k]) : 0.0f;
            }
        }
    }
    unsigned o = (unsigned)f2bf(acc.x) | ((unsigned)f2bf(acc.y) << 16);
    ((unsigned*)hb)[(size_t)wave * 64 + lane] = o;
}

// ---------------- MFMA GEMM: out = hb @ Wb^T + b (bf16 in, fp32 out) ----------------
__global__ __launch_bounds__(256) void gin_gemm_mfma(const ushort* __restrict__ hb,
                                                     const ushort* __restrict__ Wb,
                                                     const float* __restrict__ bias,
                                                     float* __restrict__ out, int nrows) {
    __shared__ ushort Wl[D * LDW];
    __shared__ ushort Al[64 * LDW];

    int tid = threadIdx.x;

    for (int i = tid; i < D * D / 8; i += 256) {
        uint4 v = ((const uint4*)Wb)[i];
        int row = i >> 4;
        int col = (i & 15) * 8;
        *(uint4*)&Wl[row * LDW + col] = v;
    }

    int base = blockIdx.x * 64;
    for (int j = tid; j < 1024; j += 256) {
        int row = j >> 4;
        int col = (j & 15) * 8;
        uint4 v = make_uint4(0, 0, 0, 0);
        if (base + row < nrows) v = *(const uint4*)&hb[(size_t)(base + row) * D + col];
        *(uint4*)&Al[row * LDW + col] = v;
    }
    __syncthreads();

    int w = tid >> 6, l = tid & 63;
    int wr = w >> 1, wc = w & 1;     // 2x2 wave grid: 32 rows x 64 cols per wave
    int lr = l & 15, hi = l >> 4;

    f32x4 acc[2][4];
#pragma unroll
    for (int m = 0; m < 2; m++)
#pragma unroll
        for (int t = 0; t < 4; t++) acc[m][t] = (f32x4)0.0f;

#pragma unroll
    for (int ks = 0; ks < 4; ks++) {
        int kof = ks * 32 + hi * 8;
        bf16x8 a0 = *(bf16x8*)&Al[(wr * 32 + lr) * LDW + kof];
        bf16x8 a1 = *(bf16x8*)&Al[(wr * 32 + 16 + lr) * LDW + kof];
#pragma unroll
        for (int t = 0; t < 4; t++) {
            bf16x8 bm = *(bf16x8*)&Wl[(wc * 64 + t * 16 + lr) * LDW + kof];
            acc[0][t] = __builtin_amdgcn_mfma_f32_16x16x32_bf16(a0, bm, acc[0][t], 0, 0, 0);
            acc[1][t] = __builtin_amdgcn_mfma_f32_16x16x32_bf16(a1, bm, acc[1][t], 0, 0, 0);
        }
    }

    // C/D layout (m89-verified): col = lane&15, row = (lane>>4)*4 + reg
#pragma unroll
    for (int m = 0; m < 2; m++) {
#pragma unroll
        for (int t = 0; t < 4; t++) {
            int col = wc * 64 + t * 16 + lr;
            float bv = bias[col];
#pragma unroll
            for (int r = 0; r < 4; r++) {
                int row = base + wr * 32 + m * 16 + hi * 4 + r;
                if (row < nrows) out[(size_t)row * D + col] = acc[m][t][r] + bv;
            }
        }
    }
}

extern "C" void kernel_launch(void* const* d_in, const int* in_sizes, int n_in,
                              void* d_out, int out_size, void* d_ws, size_t ws_size,
                              hipStream_t stream) {
    const float* x  = (const float*)d_in[0];
    const int*   ei = (const int*)d_in[1];
    const float* W  = (const float*)d_in[2];
    const float* bb = (const float*)d_in[3];
    float* out = (float*)d_out;

    int nnodes = in_sizes[0] / D;
    int nedges = in_sizes[1] / 2;
    const int* srcp = ei;
    const int* dstp = ei + nedges;

    int nb = (nnodes + 255) / 256;
    int npad = nb * 256;

    // workspace layout
    char* p = (char*)d_ws;
    int* deg     = (int*)p;  p += (size_t)npad * 4;
    int* rowptr  = (int*)p;  p += (size_t)(nnodes + 1) * 4;
    int* cursor  = (int*)p;  p += (size_t)npad * 4;
    int* csr_src = (int*)p;  p += (size_t)nedges * 4;
    p = (char*)(((uintptr_t)p + 15) & ~(uintptr_t)15);
    ushort* xb = (ushort*)p; p += (size_t)nnodes * D * 2;
    ushort* hb = (ushort*)p; p += (size_t)nnodes * D * 2;
    ushort* Wb = (ushort*)p; p += (size_t)D * D * 2;

    int n4 = nnodes * (D / 4);
    int w4 = D * D / 4;
    int ndeg4 = npad / 4;
    int eb = (nedges + 255) / 256;

    // 1) prep: zero deg + cvt x->bf16 + cvt W->bf16
    gin_prep<<<2048, 256, 0, stream>>>(x, xb, n4, W, Wb, w4, deg, ndeg4);

    // 2) hist
    gin_hist<<<eb, 256, 0, stream>>>(dstp, deg, nedges);

    // 3) scan (single kernel, redundant block-prefix)
    gin_scanall<<<nb, 256, 0, stream>>>(deg, rowptr, cursor, nnodes, nedges);

    // 4) fill
    gin_fill<<<eb, 256, 0, stream>>>(srcp, dstp, cursor, csr_src, nedges);

    // 5) gather: one wave per node, max TLP (R7 lesson: never trade wave count for fusion)
    int gb = (nnodes + 3) / 4;
    gin_gather_bf<<<gb, 256, 0, stream>>>(xb, rowptr, csr_src, hb, nnodes);

    // 6) GEMM
    int gemb = (nnodes + 63) / 64;
    gin_gemm_mfma<<<gemb, 256, 0, stream>>>(hb, Wb, bb, out, nnodes);
}

// Round 9
// 100.425 us; speedup vs baseline: 5.2752x; 1.4699x over previous
//
#include <hip/hip_runtime.h>

#define D 128
#define LDW 136   // padded LDS row (bf16 elems): +8 → 2-way bank aliasing (free, m136)
#define BM 64     // nodes per fused block

typedef __attribute__((ext_vector_type(8))) short bf16x8;
typedef __attribute__((ext_vector_type(4))) float f32x4;

static __device__ __forceinline__ ushort f2bf(float f) {
    union { float f; unsigned u; } c; c.f = f;
    unsigned u = c.u;
    return (ushort)((u + 0x7fffu + ((u >> 16) & 1u)) >> 16);  // RNE
}
static __device__ __forceinline__ float bflo(unsigned v) {
    union { unsigned u; float f; } c; c.u = v << 16; return c.f;
}
static __device__ __forceinline__ float bfhi(unsigned v) {
    union { unsigned u; float f; } c; c.u = v & 0xffff0000u; return c.f;
}

// ---------------- prep: deg = 0, xb = bf16(x), Wb = bf16(W) ----------------
__global__ __launch_bounds__(256) void gin_prep(const float* __restrict__ x,
                                                ushort* __restrict__ xb, int n4,
                                                const float* __restrict__ W,
                                                ushort* __restrict__ Wb, int w4,
                                                int* __restrict__ deg, int ndeg4) {
    int stride = gridDim.x * 256;
    int tid0 = blockIdx.x * 256 + threadIdx.x;
    for (int i = tid0; i < ndeg4; i += stride)
        ((int4*)deg)[i] = make_int4(0, 0, 0, 0);
    for (int i = tid0; i < n4; i += stride) {
        float4 v = ((const float4*)x)[i];
        ushort4 o;
        o.x = f2bf(v.x); o.y = f2bf(v.y); o.z = f2bf(v.z); o.w = f2bf(v.w);
        ((ushort4*)xb)[i] = o;
    }
    for (int i = tid0; i < w4; i += stride) {
        float4 v = ((const float4*)W)[i];
        ushort4 o;
        o.x = f2bf(v.x); o.y = f2bf(v.y); o.z = f2bf(v.z); o.w = f2bf(v.w);
        ((ushort4*)Wb)[i] = o;
    }
}

// ---------------- hist: deg[dst]++, store per-edge bucket offset r[e] ----------------
__global__ __launch_bounds__(256) void gin_hist(const int* __restrict__ dst,
                                                int* __restrict__ deg,
                                                int* __restrict__ r, int nedges) {
    int e = blockIdx.x * 256 + threadIdx.x;
    if (e < nedges) r[e] = atomicAdd(&deg[dst[e]], 1);
}

// ---------------- scanall: rowptr = exclusive_scan(deg), single kernel ----------------
// block b redundantly reduces deg[0 .. b*256) via int4 loads (<=49 indep iterations),
// then block-scans its own 256-node chunk. No cross-block communication.
__global__ __launch_bounds__(256) void gin_scanall(const int* __restrict__ deg,
                                                   int* __restrict__ rowptr,
                                                   int nnodes, int nedges) {
    __shared__ int sh[256];
    int tid = threadIdx.x;
    int bid = blockIdx.x;

    // prefix over earlier chunks: bid*256 ints = bid*64 int4s (deg is zero-padded to npad)
    int lim4 = bid * 64;
    int s = 0;
    for (int i = tid; i < lim4; i += 256) {
        int4 v = ((const int4*)deg)[i];
        s += (v.x + v.y) + (v.z + v.w);
    }
    sh[tid] = s;
    __syncthreads();
    for (int off = 128; off > 0; off >>= 1) {
        if (tid < off) sh[tid] += sh[tid + off];
        __syncthreads();
    }
    int prefix = sh[0];
    __syncthreads();

    // local inclusive scan of this chunk
    int i = bid * 256 + tid;
    int dv = (i < nnodes) ? deg[i] : 0;
    sh[tid] = dv;
    __syncthreads();
    for (int off = 1; off < 256; off <<= 1) {
        int t = (tid >= off) ? sh[tid - off] : 0;
        __syncthreads();
        sh[tid] += t;
        __syncthreads();
    }
    if (i < nnodes) rowptr[i] = prefix + sh[tid] - dv;
    if (bid == (int)gridDim.x - 1 && tid == 0) rowptr[nnodes] = nedges;
}

// ---------------- fill: csr_src[rowptr[dst] + r] = src (no atomics) ----------------
__global__ __launch_bounds__(256) void gin_fill(const int* __restrict__ src,
                                                const int* __restrict__ dst,
                                                const int* __restrict__ rowptr,
                                                const int* __restrict__ r,
                                                int* __restrict__ csr_src, int nedges) {
    int e = blockIdx.x * 256 + threadIdx.x;
    if (e < nedges) {
        int pos = rowptr[dst[e]] + r[e];
        csr_src[pos] = src[e];
    }
}

// ---------------- fused gather + MFMA GEMM, 16 waves/block ----------------
// block = 1024 thr = 16 waves, BM=64 nodes. 52 KB LDS -> 2 blocks/CU = 32 waves/CU (full).
// Gather: wave w handles nodes base+w*4 .. +4 (4 serial nodes, 8-deep edge unroll),
//         lane owns 4B (2 bf16) of the 256B row, writes straight into Al.
// GEMM: 4x4 wave grid, wave = 16 rows x 32 cols, 16x16x32 bf16 MFMA (8 MFMA/wave).
__global__ __launch_bounds__(1024) void gin_fused16(const ushort* __restrict__ xb,
                                                    const int* __restrict__ rowptr,
                                                    const int* __restrict__ csr_src,
                                                    const ushort* __restrict__ Wb,
                                                    const float* __restrict__ bias,
                                                    float* __restrict__ out, int nnodes) {
    __shared__ ushort Wl[D * LDW];    // 34816 B
    __shared__ ushort Al[BM * LDW];   // 17408 B

    int tid = threadIdx.x;
    int base = blockIdx.x * BM;

    // stage Wb (bf16, 32 KB): 2048 uint4 chunks, 2 per thread
    for (int i = tid; i < D * D / 8; i += 1024) {
        uint4 v = ((const uint4*)Wb)[i];
        int row = i >> 4;
        int col = (i & 15) * 8;
        *(uint4*)&Wl[row * LDW + col] = v;
    }

    // gather phase
    {
        int w = tid >> 6, lane = tid & 63;
        const unsigned* xbu = (const unsigned*)xb;  // 1 uint = 2 bf16
        for (int t = 0; t < 4; ++t) {
            int row = w * 4 + t;
            int node = base + row;
            unsigned ov = 0;
            if (node < nnodes) {
                int beg = rowptr[node];
                int end = rowptr[node + 1];
                unsigned sv = xbu[(size_t)node * 64 + lane];   // self term (eps=0)
                float2 acc;
                acc.x = bflo(sv);
                acc.y = bfhi(sv);
                int e = beg;
                for (; e + 8 <= end; e += 8) {
                    int s0 = csr_src[e],     s1 = csr_src[e + 1];
                    int s2 = csr_src[e + 2], s3 = csr_src[e + 3];
                    int s4 = csr_src[e + 4], s5 = csr_src[e + 5];
                    int s6 = csr_src[e + 6], s7 = csr_src[e + 7];
                    unsigned v0 = xbu[(size_t)s0 * 64 + lane];
                    unsigned v1 = xbu[(size_t)s1 * 64 + lane];
                    unsigned v2 = xbu[(size_t)s2 * 64 + lane];
                    unsigned v3 = xbu[(size_t)s3 * 64 + lane];
                    unsigned v4 = xbu[(size_t)s4 * 64 + lane];
                    unsigned v5 = xbu[(size_t)s5 * 64 + lane];
                    unsigned v6 = xbu[(size_t)s6 * 64 + lane];
                    unsigned v7 = xbu[(size_t)s7 * 64 + lane];
                    acc.x += ((bflo(v0) + bflo(v1)) + (bflo(v2) + bflo(v3)))
                           + ((bflo(v4) + bflo(v5)) + (bflo(v6) + bflo(v7)));
                    acc.y += ((bfhi(v0) + bfhi(v1)) + (bfhi(v2) + bfhi(v3)))
                           + ((bfhi(v4) + bfhi(v5)) + (bfhi(v6) + bfhi(v7)));
                }
                if (e + 4 <= end) {
                    int s0 = csr_src[e],     s1 = csr_src[e + 1];
                    int s2 = csr_src[e + 2], s3 = csr_src[e + 3];
                    unsigned v0 = xbu[(size_t)s0 * 64 + lane];
                    unsigned v1 = xbu[(size_t)s1 * 64 + lane];
                    unsigned v2 = xbu[(size_t)s2 * 64 + lane];
                    unsigned v3 = xbu[(size_t)s3 * 64 + lane];
                    acc.x += (bflo(v0) + bflo(v1)) + (bflo(v2) + bflo(v3));
                    acc.y += (bfhi(v0) + bfhi(v1)) + (bfhi(v2) + bfhi(v3));
                    e += 4;
                }
                for (; e < end; ++e) {
                    unsigned v = xbu[(size_t)csr_src[e] * 64 + lane];
                    acc.x += bflo(v);
                    acc.y += bfhi(v);
                }
                ov = (unsigned)f2bf(acc.x) | ((unsigned)f2bf(acc.y) << 16);
            }
            *(unsigned*)&Al[row * LDW + lane * 2] = ov;  // 64 lanes x 4B consecutive: conflict-free
        }
    }
    __syncthreads();

    // MFMA phase: 4x4 wave grid
    int w = tid >> 6, l = tid & 63;
    int wr = w >> 2, wc = w & 3;     // wave: rows [wr*16,+16), cols [wc*32,+32)
    int lr = l & 15, hi = l >> 4;

    f32x4 acc[2];
    acc[0] = (f32x4)0.0f;
    acc[1] = (f32x4)0.0f;

#pragma unroll
    for (int ks = 0; ks < 4; ks++) {
        int kof = ks * 32 + hi * 8;
        bf16x8 a = *(bf16x8*)&Al[(wr * 16 + lr) * LDW + kof];
#pragma unroll
        for (int t = 0; t < 2; t++) {
            bf16x8 bm = *(bf16x8*)&Wl[(wc * 32 + t * 16 + lr) * LDW + kof];
            acc[t] = __builtin_amdgcn_mfma_f32_16x16x32_bf16(a, bm, acc[t], 0, 0, 0);
        }
    }

    // C/D layout (m89-verified): col = lane&15, row = (lane>>4)*4 + reg
#pragma unroll
    for (int t = 0; t < 2; t++) {
        int col = wc * 32 + t * 16 + lr;
        float bv = bias[col];
#pragma unroll
        for (int rr = 0; rr < 4; rr++) {
            int row = base + wr * 16 + hi * 4 + rr;
            if (row < nnodes) out[(size_t)row * D + col] = acc[t][rr] + bv;
        }
    }
}

extern "C" void kernel_launch(void* const* d_in, const int* in_sizes, int n_in,
                              void* d_out, int out_size, void* d_ws, size_t ws_size,
                              hipStream_t stream) {
    const float* x  = (const float*)d_in[0];
    const int*   ei = (const int*)d_in[1];
    const float* W  = (const float*)d_in[2];
    const float* bb = (const float*)d_in[3];
    float* out = (float*)d_out;

    int nnodes = in_sizes[0] / D;
    int nedges = in_sizes[1] / 2;
    const int* srcp = ei;
    const int* dstp = ei + nedges;

    int nb = (nnodes + 255) / 256;
    int npad = nb * 256;

    // workspace layout
    char* p = (char*)d_ws;
    int* deg     = (int*)p;  p += (size_t)npad * 4;         // zero-padded to npad
    int* rowptr  = (int*)p;  p += (size_t)(nnodes + 1) * 4;
    int* redge   = (int*)p;  p += (size_t)nedges * 4;       // per-edge bucket offset
    int* csr_src = (int*)p;  p += (size_t)nedges * 4;
    p = (char*)(((uintptr_t)p + 15) & ~(uintptr_t)15);
    ushort* xb = (ushort*)p; p += (size_t)nnodes * D * 2;
    ushort* Wb = (ushort*)p; p += (size_t)D * D * 2;

    int n4 = nnodes * (D / 4);
    int w4 = D * D / 4;
    int ndeg4 = npad / 4;
    int eb = (nedges + 255) / 256;

    // 1) prep: zero deg + cvt x->bf16 + cvt W->bf16
    gin_prep<<<2048, 256, 0, stream>>>(x, xb, n4, W, Wb, w4, deg, ndeg4);

    // 2) hist (+ per-edge offsets)
    gin_hist<<<eb, 256, 0, stream>>>(dstp, deg, redge, nedges);

    // 3) scan (single kernel, int4-vectorized redundant block-prefix)
    gin_scanall<<<nb, 256, 0, stream>>>(deg, rowptr, nnodes, nedges);

    // 4) fill (no atomics)
    gin_fill<<<eb, 256, 0, stream>>>(srcp, dstp, rowptr, redge, csr_src, nedges);

    // 5) fused gather + GEMM: 16 waves/block, 32 waves/CU (R7 failure mode fixed)
    int gemb = (nnodes + BM - 1) / BM;
    gin_fused16<<<gemb, 1024, 0, stream>>>(xb, rowptr, csr_src, Wb, bb, out, nnodes);
}